// Round 6
// baseline (244.932 us; speedup 1.0000x reference)
//
#include <hip/hip_runtime.h>

typedef __attribute__((ext_vector_type(8))) short short8;
typedef __attribute__((ext_vector_type(4))) float float4v;

__device__ __forceinline__ unsigned short f2bf(float f) {
  unsigned int u = __float_as_uint(f);
  u += 0x7fffu + ((u >> 16) & 1u);   // round-to-nearest-even
  return (unsigned short)(u >> 16);
}
__device__ __forceinline__ float bf2f(unsigned short h) {
  return __uint_as_float(((unsigned int)h) << 16);
}
__device__ __forceinline__ unsigned int pack2bf(float a, float b) {
  return (unsigned int)f2bf(a) | ((unsigned int)f2bf(b) << 16);
}

// ---------------- prep: w' = gamma*w -> bf16 [n][k'] + colsum + bias ----------
// k' = c*8 + i (i = di*4+hi*2+wi), k_orig = i*96 + c
__global__ __launch_bounds__(256)
void prep_kernel(const float* __restrict__ w_red, const float* __restrict__ gamma,
                 const float* __restrict__ beta, unsigned short* __restrict__ w_bf,
                 float* __restrict__ colsum, float* __restrict__ bias) {
  const int n = blockIdx.x;       // 0..191
  const int t = threadIdx.x;      // 0..255
  float cs = 0.f, bs = 0.f;
#pragma unroll
  for (int j = 0; j < 3; ++j) {
    int kp = j * 256 + t;                       // k' 0..767
    int ko = (kp & 7) * 96 + (kp >> 3);         // original k
    float w = w_red[(size_t)ko * 192 + n];
    unsigned short v = f2bf(gamma[ko] * w);
    w_bf[(size_t)n * 768 + kp] = v;
    cs += bf2f(v);
    bs += beta[ko] * w;
  }
#pragma unroll
  for (int off = 1; off < 64; off <<= 1) {
    cs += __shfl_xor(cs, off, 64);
    bs += __shfl_xor(bs, off, 64);
  }
  __shared__ float red[2][4];
  const int wave = t >> 6;
  if ((t & 63) == 0) { red[0][wave] = cs; red[1][wave] = bs; }
  __syncthreads();
  if (t == 0) {
    colsum[n] = red[0][0] + red[0][1] + red[0][2] + red[0][3];
    bias[n]   = red[1][0] + red[1][1] + red[1][2] + red[1][3];
  }
}

// ---------------- kernel A: gather + LN stats + bf16 pack -> Yg --------------
// Block = 16 output pixels (p = bid*16 + row). Pure streaming: no GEMM phase.
// Yg layout: [p][k'] row-major, 768 bf16 per row.
__global__ __launch_bounds__(256, 3)
void gather_kernel(const float* __restrict__ x, unsigned short* __restrict__ Yg,
                   float* __restrict__ mu_g, float* __restrict__ rs_g) {
  __shared__ __align__(16) float Yf[12288];   // 48 KiB staging; bf16 overlay later
  __shared__ float4 part4[4][8];

  const int tid = threadIdx.x;
  const int bid = blockIdx.x;
  const int b  = bid >> 10;
  const int dz = (bid >> 6) & 15;
  const int hy = (bid >> 1) & 31;
  const int wh = bid & 1;

  const float* xb = x + (size_t)b * 12582912u + (size_t)dz * 8192u
                      + (size_t)hy * 128u + wh * 32;

  // Thread map: r0 = tid>>3 -> (c0, di, hi); 8 lanes cover 128B contiguous.
  const int r0 = tid >> 3;
  const int c0 = r0 >> 2;          // 0..7 (wave w covers c0 = 2w, 2w+1)
  const int di = (r0 >> 1) & 1;
  const int hi = r0 & 1;
  const int w0 = (tid & 7) << 2;
  const float* xp = xb + (size_t)c0 * 131072u + di * 4096 + hi * 64 + w0;

  const int lane = tid & 63;
  const int wave = tid >> 6;

  // Phase A: 12 async 16B/lane loads into load-order LDS (zero VGPR cost).
  {
    const float* ldsbase = &Yf[wave * 3072];   // wave-uniform
#pragma unroll
    for (int it = 0; it < 12; ++it) {
      __builtin_amdgcn_global_load_lds(
          (const __attribute__((address_space(1))) unsigned int*)(xp + (size_t)it * 1048576u),
          (__attribute__((address_space(3))) unsigned int*)(ldsbase + it * 256),
          16, 0, 0);
    }
  }
  __syncthreads();   // drain: all x data in LDS

  // Phase C: read back own float4s (conflict-free), stats + bf16 pack in regs.
  unsigned int pr0[12], pr1[12];
  float sum0 = 0.f, sq0 = 0.f, sum1 = 0.f, sq1 = 0.f;
#pragma unroll
  for (int it = 0; it < 12; ++it) {
    float4 vv = *(const float4*)&Yf[(wave * 12 + it) * 256 + lane * 4];
    pr0[it] = pack2bf(vv.x, vv.y);
    pr1[it] = pack2bf(vv.z, vv.w);
    sum0 += vv.x + vv.y;  sq0 += vv.x * vv.x + vv.y * vv.y;
    sum1 += vv.z + vv.w;  sq1 += vv.z * vv.z + vv.w * vv.w;
  }
#pragma unroll
  for (int off = 8; off < 64; off <<= 1) {
    sum0 += __shfl_xor(sum0, off, 64);  sq0 += __shfl_xor(sq0, off, 64);
    sum1 += __shfl_xor(sum1, off, 64);  sq1 += __shfl_xor(sq1, off, 64);
  }
  if (lane < 8) part4[wave][lane] = make_float4(sum0, sq0, sum1, sq1);

  __syncthreads();   // f32 reads done -> safe to overwrite with bf16 overlay

  // Phase E: write packed bf16 into Y[16][776] overlay (776 pad kills conflicts).
  unsigned short (*Y)[776] = (unsigned short (*)[776])Yf;
  const int wx0 = (tid & 7) << 1;
  const int k00 = c0 * 8 + di * 4 + hi * 2;
#pragma unroll
  for (int it = 0; it < 12; ++it) {
    int k0 = it * 64 + k00;
    *(unsigned int*)&Y[wx0][k0]     = pr0[it];
    *(unsigned int*)&Y[wx0 + 1][k0] = pr1[it];
  }

  // Stats -> global (pixel p = bid*16 + tid for tid<16).
  if (tid < 16) {
    int l = tid >> 1, odd = tid & 1;
    float s = 0.f, q = 0.f;
#pragma unroll
    for (int w = 0; w < 4; ++w) {
      float4 p = part4[w][l];
      s += odd ? p.z : p.x;
      q += odd ? p.w : p.y;
    }
    float mu  = s * (1.f / 768.f);
    float var = q * (1.f / 768.f) - mu * mu;
    mu_g[bid * 16 + tid] = mu;
    rs_g[bid * 16 + tid] = rsqrtf(var + 1e-5f);
  }

  __syncthreads();   // overlay complete

  // Copy-out: 16 rows x 1536B, fully coalesced (1 KiB/wave-instr).
  unsigned short* yrow = Yg + (size_t)bid * 12288u;   // 16*768
#pragma unroll
  for (int it = 0; it < 6; ++it) {
    int o   = it * 256 + tid;        // float4 index 0..1535
    int row = o / 96;                // 96 float4s per 768-short row
    int col = o - row * 96;
    float4 vv = *(const float4*)&Y[row][col * 8];
    *(float4*)(yrow + row * 768 + col * 8) = vv;
  }
}

// ---------------- kernel B: barrier-free GEMM Y[32768x768] x W^T[192x768] ----
// Block = 64 pixels; wave = 16 pixels x all 192 channels (12 n-tiles).
// B k-slice (12KB) shared by all waves -> L1-served after first toucher.
__global__ __launch_bounds__(256, 2)
void gemm_kernel(const unsigned short* __restrict__ Yg,
                 const unsigned short* __restrict__ w_bf,
                 const float* __restrict__ mu_g, const float* __restrict__ rs_g,
                 const float* __restrict__ colsum, const float* __restrict__ bias,
                 float* __restrict__ out) {
  const int tid  = threadIdx.x;
  const int lane = tid & 63;
  const int wave = tid >> 6;
  const int lrow = lane & 15;
  const int lq   = lane >> 4;
  const int m0   = blockIdx.x * 64 + wave * 16;   // wave's first pixel

  const unsigned short* arow = Yg + (size_t)(m0 + lrow) * 768 + lq * 8;
  const unsigned short* brow = w_bf + (size_t)lrow * 768 + lq * 8;

  float4v acc[12];
#pragma unroll
  for (int j = 0; j < 12; ++j)
#pragma unroll
    for (int r = 0; r < 4; ++r) acc[j][r] = 0.f;

  short8 a_cur = *(const short8*)(arow);
  short8 b_cur[12];
#pragma unroll
  for (int j = 0; j < 12; ++j) b_cur[j] = *(const short8*)(brow + (size_t)j * 12288u);

  for (int kc = 0; kc < 24; ++kc) {
    int kn = (kc + 1 < 24) ? kc + 1 : 23;
    short8 a_nxt = *(const short8*)(arow + kn * 32);
    short8 b_nxt[12];
#pragma unroll
    for (int j = 0; j < 12; ++j)
      b_nxt[j] = *(const short8*)(brow + (size_t)j * 12288u + kn * 32);
#pragma unroll
    for (int j = 0; j < 12; ++j)
      acc[j] = __builtin_amdgcn_mfma_f32_16x16x32_bf16(a_cur, b_cur[j], acc[j], 0, 0, 0);
    a_cur = a_nxt;
#pragma unroll
    for (int j = 0; j < 12; ++j) b_cur[j] = b_nxt[j];
  }

  // Epilogue: LN fold via colsum trick; lane's 4 acc regs = 4 consecutive pixels.
  float4 mu4 = *(const float4*)&mu_g[m0 + lq * 4];
  float4 rs4 = *(const float4*)&rs_g[m0 + lq * 4];
  const int bb   = m0 >> 14;
  const int rem  = m0 & 16383;
  const int dz   = rem >> 10;
  const int rem2 = rem & 1023;       // hy*32 + w0 (w0 in {0,16})
  float* ob = out + (size_t)bb * 3145728u + (size_t)dz * 1024u + rem2 + lq * 4;
#pragma unroll
  for (int j = 0; j < 12; ++j) {
    int n = j * 16 + lrow;
    float cs = colsum[n], bi = bias[n];
    float4 vv;
    vv.x = rs4.x * (acc[j][0] - mu4.x * cs) + bi;
    vv.y = rs4.y * (acc[j][1] - mu4.y * cs) + bi;
    vv.z = rs4.z * (acc[j][2] - mu4.z * cs) + bi;
    vv.w = rs4.w * (acc[j][3] - mu4.w * cs) + bi;
    *(float4*)(ob + (size_t)n * 16384u) = vv;
  }
}

// ---------------- fallback: R1 single-kernel path (77.5us proven) ------------
__global__ __launch_bounds__(256, 3)
void pm_fallback(const float* __restrict__ x, const unsigned short* __restrict__ w_bf,
                 const float* __restrict__ colsum, const float* __restrict__ bias,
                 float* __restrict__ out) {
  __shared__ __align__(16) unsigned short Y[32][776];
  __shared__ float4 part4[4][16];
  __shared__ float smu[32], srs[32];

  const int tid = threadIdx.x;
  const int bid = blockIdx.x;
  const int b  = bid >> 9;
  const int dz = (bid >> 5) & 15;
  const int hy = bid & 31;

  const float* xb = x + (size_t)b * 12582912u + (size_t)dz * 8192u + (size_t)hy * 128u;
  const int r0 = tid >> 4;
  const int c0 = r0 >> 2;
  const int di = (r0 >> 1) & 1;
  const int hi = r0 & 1;
  const int w0 = (tid & 15) << 2;
  const float* xp = xb + (size_t)c0 * 131072u + di * 4096 + hi * 64 + w0;

  float4 v[24];
#pragma unroll
  for (int it = 0; it < 24; ++it)
    v[it] = *(const float4*)(xp + (size_t)it * 524288u);

  const int lane = tid & 63;
  const int wave = tid >> 6;
  const int lrow = lane & 15;
  const int lq   = lane >> 4;
  const unsigned short* wrow[3];
#pragma unroll
  for (int t3 = 0; t3 < 3; ++t3)
    wrow[t3] = w_bf + (size_t)((wave * 3 + t3) * 16 + lrow) * 768 + lq * 8;
  short8 b0[3], b1[3];
#pragma unroll
  for (int t3 = 0; t3 < 3; ++t3) b0[t3] = *(const short8*)(wrow[t3]);
#pragma unroll
  for (int t3 = 0; t3 < 3; ++t3) b1[t3] = *(const short8*)(wrow[t3] + 32);

  const int wx0 = (tid & 15) << 1;
  const int k00 = c0 * 8 + di * 4 + hi * 2;
  float sum0 = 0.f, sq0 = 0.f, sum1 = 0.f, sq1 = 0.f;
#pragma unroll
  for (int it = 0; it < 24; ++it) {
    float4 vv = v[it];
    unsigned int p01 = pack2bf(vv.x, vv.y);
    unsigned int p23 = pack2bf(vv.z, vv.w);
    int k0 = it * 32 + k00;
    *(unsigned int*)&Y[wx0][k0]     = p01;
    *(unsigned int*)&Y[wx0 + 1][k0] = p23;
    sum0 += vv.x + vv.y;  sq0 += vv.x * vv.x + vv.y * vv.y;
    sum1 += vv.z + vv.w;  sq1 += vv.z * vv.z + vv.w * vv.w;
  }
#pragma unroll
  for (int off = 16; off < 64; off <<= 1) {
    sum0 += __shfl_xor(sum0, off, 64);  sq0 += __shfl_xor(sq0, off, 64);
    sum1 += __shfl_xor(sum1, off, 64);  sq1 += __shfl_xor(sq1, off, 64);
  }
  if (lane < 16) part4[wave][lane] = make_float4(sum0, sq0, sum1, sq1);
  __syncthreads();

  if (tid < 32) {
    int sp = tid >> 1, odd = tid & 1;
    float s = 0.f, q = 0.f;
#pragma unroll
    for (int w = 0; w < 4; ++w) {
      float4 p = part4[w][sp];
      s += odd ? p.z : p.x;
      q += odd ? p.w : p.y;
    }
    float mu  = s * (1.f / 768.f);
    float var = q * (1.f / 768.f) - mu * mu;
    smu[tid] = mu;
    srs[tid] = rsqrtf(var + 1e-5f);
  }

  float4v acc[2][3];
#pragma unroll
  for (int i2 = 0; i2 < 2; ++i2)
#pragma unroll
    for (int j2 = 0; j2 < 3; ++j2)
#pragma unroll
      for (int r = 0; r < 4; ++r) acc[i2][j2][r] = 0.f;

  for (int kc = 0; kc < 24; ++kc) {
    int kn = (kc + 2 <= 23) ? kc + 2 : 23;
    short8 b2[3];
#pragma unroll
    for (int t3 = 0; t3 < 3; ++t3) b2[t3] = *(const short8*)(wrow[t3] + kn * 32);
    short8 a0 = *(const short8*)&Y[lrow][kc * 32 + lq * 8];
    short8 a1 = *(const short8*)&Y[16 + lrow][kc * 32 + lq * 8];
#pragma unroll
    for (int t3 = 0; t3 < 3; ++t3) {
      acc[0][t3] = __builtin_amdgcn_mfma_f32_16x16x32_bf16(a0, b0[t3], acc[0][t3], 0, 0, 0);
      acc[1][t3] = __builtin_amdgcn_mfma_f32_16x16x32_bf16(a1, b0[t3], acc[1][t3], 0, 0, 0);
    }
#pragma unroll
    for (int t3 = 0; t3 < 3; ++t3) { b0[t3] = b1[t3]; b1[t3] = b2[t3]; }
  }

  float cs_n[3], bi_n[3];
#pragma unroll
  for (int t3 = 0; t3 < 3; ++t3) {
    int ng = (wave * 3 + t3) * 16 + lrow;
    cs_n[t3] = colsum[ng];
    bi_n[t3] = bias[ng];
  }

  __syncthreads();
  float* Cs = (float*)&Y[0][0];
#pragma unroll
  for (int t3 = 0; t3 < 3; ++t3) {
    int ng = (wave * 3 + t3) * 16 + lrow;
#pragma unroll
    for (int mt = 0; mt < 2; ++mt)
#pragma unroll
      for (int r = 0; r < 4; ++r) {
        int m = mt * 16 + lq * 4 + r;
        float vv = srs[m] * (acc[mt][t3][r] - smu[m] * cs_n[t3]) + bi_n[t3];
        Cs[ng * 40 + m] = vv;
      }
  }
  __syncthreads();

  float* ob = out + (size_t)b * 3145728u + (size_t)dz * 1024u + (size_t)hy * 32u;
#pragma unroll
  for (int it = 0; it < 6; ++it) {
    int idx4 = it * 256 + tid;
    int o  = idx4 >> 3;
    int wq = idx4 & 7;
    float4 vv = *(const float4*)&Cs[o * 40 + wq * 4];
    *(float4*)(ob + (size_t)o * 16384u + wq * 4) = vv;
  }
}

extern "C" void kernel_launch(void* const* d_in, const int* in_sizes, int n_in,
                              void* d_out, int out_size, void* d_ws, size_t ws_size,
                              hipStream_t stream) {
  const float* x     = (const float*)d_in[0];
  const float* gamma = (const float*)d_in[1];
  const float* beta  = (const float*)d_in[2];
  const float* w_red = (const float*)d_in[3];
  float* out = (float*)d_out;

  const size_t Y_BYTES = 50331648u;    // 32768*768*2
  const size_t NEED = Y_BYTES + 294912u + 768u + 768u + 131072u + 131072u;

  if (ws_size >= NEED) {
    unsigned short* Yg   = (unsigned short*)d_ws;
    unsigned short* w_bf = (unsigned short*)((char*)d_ws + Y_BYTES);
    float* colsum = (float*)((char*)d_ws + Y_BYTES + 294912u);
    float* bias   = colsum + 192;
    float* mu_g   = (float*)((char*)d_ws + Y_BYTES + 294912u + 1536u);
    float* rs_g   = mu_g + 32768;

    prep_kernel<<<dim3(192), dim3(256), 0, stream>>>(w_red, gamma, beta, w_bf, colsum, bias);
    gather_kernel<<<dim3(2048), dim3(256), 0, stream>>>(x, Yg, mu_g, rs_g);
    gemm_kernel<<<dim3(512), dim3(256), 0, stream>>>(Yg, w_bf, mu_g, rs_g, colsum, bias, out);
  } else {
    unsigned short* w_bf = (unsigned short*)d_ws;
    float* colsum = (float*)((char*)d_ws + 294912u);
    float* bias   = colsum + 192;
    prep_kernel<<<dim3(192), dim3(256), 0, stream>>>(w_red, gamma, beta, w_bf, colsum, bias);
    pm_fallback<<<dim3(1024), dim3(256), 0, stream>>>(x, w_bf, colsum, bias, out);
  }
}

// Round 7
// 197.302 us; speedup vs baseline: 1.2414x; 1.2414x over previous
//
#include <hip/hip_runtime.h>

typedef __attribute__((ext_vector_type(8))) short short8;
typedef __attribute__((ext_vector_type(4))) float float4v;

__device__ __forceinline__ unsigned short f2bf(float f) {
  unsigned int u = __float_as_uint(f);
  u += 0x7fffu + ((u >> 16) & 1u);   // round-to-nearest-even
  return (unsigned short)(u >> 16);
}
__device__ __forceinline__ float bf2f(unsigned short h) {
  return __uint_as_float(((unsigned int)h) << 16);
}
__device__ __forceinline__ unsigned int pack2bf(float a, float b) {
  return (unsigned int)f2bf(a) | ((unsigned int)f2bf(b) << 16);
}

// ---- prep: w' = gamma*w -> bf16 in MFMA FRAGMENT ORDER + colsum + bias ------
// w_frag[((ntile*24 + kc)*64 + lq*16 + lrow)*8 + e]; n = ntile*16+lrow,
// k' = kc*32 + lq*8 + e; k_orig = (k'&7)*96 + (k'>>3).
__global__ __launch_bounds__(256)
void prep_kernel(const float* __restrict__ w_red, const float* __restrict__ gamma,
                 const float* __restrict__ beta, unsigned short* __restrict__ w_frag,
                 float* __restrict__ colsum, float* __restrict__ bias) {
  const int n = blockIdx.x;       // 0..191
  const int t = threadIdx.x;      // 0..255
  const int ntile = n >> 4, lrow = n & 15;
  float cs = 0.f, bs = 0.f;
#pragma unroll
  for (int j = 0; j < 3; ++j) {
    int kp = j * 256 + t;                       // k' 0..767
    int ko = (kp & 7) * 96 + (kp >> 3);         // original k
    float w = w_red[(size_t)ko * 192 + n];
    unsigned short v = f2bf(gamma[ko] * w);
    int kc = kp >> 5, r = kp & 31, lq = r >> 3, e = r & 7;
    w_frag[(size_t)((ntile * 24 + kc) * 64 + lq * 16 + lrow) * 8 + e] = v;
    cs += bf2f(v);
    bs += beta[ko] * w;
  }
#pragma unroll
  for (int off = 1; off < 64; off <<= 1) {
    cs += __shfl_xor(cs, off, 64);
    bs += __shfl_xor(bs, off, 64);
  }
  __shared__ float red[2][4];
  const int wave = t >> 6;
  if ((t & 63) == 0) { red[0][wave] = cs; red[1][wave] = bs; }
  __syncthreads();
  if (t == 0) {
    colsum[n] = red[0][0] + red[0][1] + red[0][2] + red[0][3];
    bias[n]   = red[1][0] + red[1][1] + red[1][2] + red[1][3];
  }
}

// ---- main: fused, software-pipelined (counted vmcnt, raw barriers) ----------
// Block = 16 px; 12 chunks of 64 k. Per phase: DMA chunk it+2 | load B(it+1)
// | vmcnt(7) | pack(it+1)+stats | 6 MFMA on chunk it. 1 barrier/phase.
__global__ __launch_bounds__(256, 2)
void pm_kernel(const float* __restrict__ x, const unsigned short* __restrict__ w_frag,
               const float* __restrict__ colsum, const float* __restrict__ bias,
               float* __restrict__ out) {
  __shared__ __align__(16) float F[3072];            // 3 slots x 1024 f32 (12 KB)
  __shared__ __align__(16) unsigned short Yb[2048];  // 2 slots x 16px x 64k bf16 (4 KB)
  __shared__ float4 part4[4][8];
  __shared__ float smu[16], srs[16];

  const int tid = threadIdx.x;
  const int bid = blockIdx.x;
  const int b  = bid >> 10;
  const int dz = (bid >> 6) & 15;
  const int hy = (bid >> 1) & 31;
  const int wh = bid & 1;

  const float* xb = x + (size_t)b * 12582912u + (size_t)dz * 8192u
                      + (size_t)hy * 128u + wh * 32;
  const int r0 = tid >> 3;
  const int c0 = r0 >> 2;          // 0..7; chunk channel c = c0 + 8*it
  const int di = (r0 >> 1) & 1;
  const int hi = r0 & 1;
  const int w0 = (tid & 7) << 2;
  const float* xp = xb + (size_t)c0 * 131072u + di * 4096 + hi * 64 + w0;

  const int lane = tid & 63;
  const int wave = tid >> 6;
  const int lrow = lane & 15;
  const int lq   = lane >> 4;

  // LDS addressing (bytes). A-tile rows are 128 B -> XOR-swizzle (G4).
  char* ybase = (char*)Yb;
  const int wx0 = (tid & 7) << 1;                  // px row pair written by thread
  const int k00 = c0 * 8 + di * 4 + hi * 2;        // chunk-local k (const!)
  const int b0off = (wx0 * 128 + k00 * 2) ^ ((wx0 & 7) << 4);
  const int b1off = ((wx0 + 1) * 128 + k00 * 2) ^ (((wx0 + 1) & 7) << 4);
  const int ra0 = (lrow * 128 + lq * 16) ^ ((lrow & 7) << 4);        // ks=0
  const int ra1 = (lrow * 128 + 64 + lq * 16) ^ ((lrow & 7) << 4);   // ks=1
  const int fth = wave * 256 + lane * 4;   // thread's float4 in an F slot
  const int fwv = wave * 256;              // wave-uniform DMA dest in an F slot

  // B fragment pointers (fragment-order w_frag -> contiguous 1KB/wave loads).
  const unsigned short* wb0 = w_frag + (size_t)(wave * 3 + 0) * 12288u + lane * 8;
  const unsigned short* wb1 = w_frag + (size_t)(wave * 3 + 1) * 12288u + lane * 8;
  const unsigned short* wb2 = w_frag + (size_t)(wave * 3 + 2) * 12288u + lane * 8;

  short8 bA[6], bB[6];
  float4v acc[3];
#pragma unroll
  for (int j = 0; j < 3; ++j)
#pragma unroll
    for (int r = 0; r < 4; ++r) acc[j][r] = 0.f;
  float sum0 = 0.f, sq0 = 0.f, sum1 = 0.f, sq1 = 0.f;

#define DMA(IT, SL)                                                            \
  __builtin_amdgcn_global_load_lds(                                            \
      (const __attribute__((address_space(1))) unsigned int*)(xp + (size_t)(IT) * 1048576u), \
      (__attribute__((address_space(3))) unsigned int*)&F[(SL) * 1024 + fwv], 16, 0, 0)

#define LOADB(BN, ITB)                                                         \
  do {                                                                         \
    const unsigned short* kp0 = wb0 + (ITB) * 1024;                            \
    BN[0] = *(const short8*)(kp0);                                             \
    BN[1] = *(const short8*)(kp0 + 512);                                       \
    const unsigned short* kp1 = wb1 + (ITB) * 1024;                            \
    BN[2] = *(const short8*)(kp1);                                             \
    BN[3] = *(const short8*)(kp1 + 512);                                       \
    const unsigned short* kp2 = wb2 + (ITB) * 1024;                            \
    BN[4] = *(const short8*)(kp2);                                             \
    BN[5] = *(const short8*)(kp2 + 512);                                       \
  } while (0)

#define PACK(SLP, PN)                                                          \
  do {                                                                         \
    float4 vv = *(const float4*)&F[(SLP) * 1024 + fth];                        \
    *(unsigned int*)(ybase + (PN) * 2048 + b0off) = pack2bf(vv.x, vv.y);       \
    *(unsigned int*)(ybase + (PN) * 2048 + b1off) = pack2bf(vv.z, vv.w);       \
    sum0 += vv.x + vv.y;  sq0 += vv.x * vv.x + vv.y * vv.y;                    \
    sum1 += vv.z + vv.w;  sq1 += vv.z * vv.z + vv.w * vv.w;                    \
  } while (0)

#define PHASE(IT, PC, PN, BC, BN, SLI, SLP)                                    \
  do {                                                                         \
    asm volatile("s_waitcnt lgkmcnt(0)" ::: "memory");                         \
    __builtin_amdgcn_s_barrier();                                              \
    { int itn = (IT) + 2 <= 11 ? (IT) + 2 : 11; DMA(itn, SLI); }               \
    { int itb = (IT) + 1 <= 11 ? (IT) + 1 : 11; LOADB(BN, itb); }              \
    asm volatile("s_waitcnt vmcnt(7)" ::: "memory");                           \
    if ((IT) < 11) PACK(SLP, PN);                                              \
    { short8 a0 = *(const short8*)(ybase + (PC) * 2048 + ra0);                 \
      short8 a1 = *(const short8*)(ybase + (PC) * 2048 + ra1);                 \
      acc[0] = __builtin_amdgcn_mfma_f32_16x16x32_bf16(a0, BC[0], acc[0], 0, 0, 0); \
      acc[0] = __builtin_amdgcn_mfma_f32_16x16x32_bf16(a1, BC[1], acc[0], 0, 0, 0); \
      acc[1] = __builtin_amdgcn_mfma_f32_16x16x32_bf16(a0, BC[2], acc[1], 0, 0, 0); \
      acc[1] = __builtin_amdgcn_mfma_f32_16x16x32_bf16(a1, BC[3], acc[1], 0, 0, 0); \
      acc[2] = __builtin_amdgcn_mfma_f32_16x16x32_bf16(a0, BC[4], acc[2], 0, 0, 0); \
      acc[2] = __builtin_amdgcn_mfma_f32_16x16x32_bf16(a1, BC[5], acc[2], 0, 0, 0); } \
  } while (0)

  // Prologue: L(0)->slot0, L(1)->slot1, B(0); vmcnt(7) completes exactly L(0).
  DMA(0, 0);
  asm volatile("" ::: "memory");
  DMA(1, 1);
  asm volatile("" ::: "memory");
  LOADB(bA, 0);
  asm volatile("s_waitcnt vmcnt(7)" ::: "memory");
  PACK(0, 0);   // chunk 0 -> Yb parity 0

  // 12 phases; slot pattern period 6; parity period 2. Steady-state queue at
  // each phase entry: [L(it+1), B(it)x6] = 7 outstanding.
#pragma unroll
  for (int it6 = 0; it6 < 12; it6 += 6) {
    PHASE(it6 + 0, 0, 1, bA, bB, 2, 1);
    PHASE(it6 + 1, 1, 0, bB, bA, 0, 2);
    PHASE(it6 + 2, 0, 1, bA, bB, 1, 0);
    PHASE(it6 + 3, 1, 0, bB, bA, 2, 1);
    PHASE(it6 + 4, 0, 1, bA, bB, 0, 2);
    PHASE(it6 + 5, 1, 0, bB, bA, 1, 0);
  }
#undef PHASE
#undef PACK
#undef LOADB
#undef DMA

  // LN stats: reduce over lanes sharing a px-row-pair, then across waves.
#pragma unroll
  for (int off = 8; off < 64; off <<= 1) {
    sum0 += __shfl_xor(sum0, off, 64);  sq0 += __shfl_xor(sq0, off, 64);
    sum1 += __shfl_xor(sum1, off, 64);  sq1 += __shfl_xor(sq1, off, 64);
  }
  if (lane < 8) part4[wave][lane] = make_float4(sum0, sq0, sum1, sq1);
  __syncthreads();

  if (tid < 16) {
    int l = tid >> 1, odd = tid & 1;
    float s = 0.f, q = 0.f;
#pragma unroll
    for (int w = 0; w < 4; ++w) {
      float4 p = part4[w][l];
      s += odd ? p.z : p.x;
      q += odd ? p.w : p.y;
    }
    float mu  = s * (1.f / 768.f);
    float var = q * (1.f / 768.f) - mu * mu;
    smu[tid] = mu;
    srs[tid] = rsqrtf(var + 1e-5f);
  }
  __syncthreads();

  // Epilogue: LN folded via colsum trick; lane's 4 acc regs = 4 consecutive px.
  float4 mu4 = *(const float4*)&smu[lq * 4];
  float4 rs4 = *(const float4*)&srs[lq * 4];
  float* ob = out + (size_t)b * 3145728u + (size_t)dz * 1024u
                  + (size_t)hy * 32u + wh * 16 + lq * 4;
#pragma unroll
  for (int j = 0; j < 3; ++j) {
    int n = (wave * 3 + j) * 16 + lrow;
    float cs = colsum[n], bi = bias[n];
    float4 vv;
    vv.x = rs4.x * (acc[j][0] - mu4.x * cs) + bi;
    vv.y = rs4.y * (acc[j][1] - mu4.y * cs) + bi;
    vv.z = rs4.z * (acc[j][2] - mu4.z * cs) + bi;
    vv.w = rs4.w * (acc[j][3] - mu4.w * cs) + bi;
    *(float4*)(ob + (size_t)n * 16384u) = vv;
  }
}

extern "C" void kernel_launch(void* const* d_in, const int* in_sizes, int n_in,
                              void* d_out, int out_size, void* d_ws, size_t ws_size,
                              hipStream_t stream) {
  const float* x     = (const float*)d_in[0];
  const float* gamma = (const float*)d_in[1];
  const float* beta  = (const float*)d_in[2];
  const float* w_red = (const float*)d_in[3];
  float* out = (float*)d_out;

  unsigned short* w_frag = (unsigned short*)d_ws;          // 192*768*2 = 294912 B
  float* colsum = (float*)((char*)d_ws + 294912);          // 192 f32
  float* bias   = colsum + 192;                            // 192 f32

  prep_kernel<<<dim3(192), dim3(256), 0, stream>>>(w_red, gamma, beta, w_frag, colsum, bias);
  pm_kernel<<<dim3(2048), dim3(256), 0, stream>>>(x, w_frag, colsum, bias, out);
}